// Round 2
// baseline (1165.488 us; speedup 1.0000x reference)
//
#include <hip/hip_runtime.h>
#include <hip/hip_bf16.h>
#include <stdint.h>

// ---------------------------------------------------------------------------
// SparseQuantLinear: out[m,o] = sum_i x[m,i] * W[o,i] + bias[o]
//   W[o,i] = mask[o,i] ? (W_q[o,i] - zeros[o,i/G]) * scales[o,i/G] * scale2[i] : 0
// Plan: dequant W -> bf16 in d_ws (32 MB), then bf16 MFMA GEMM (x converted
// fp32->bf16 during LDS staging). M=16384, N=O=4096, K=I=4096, G=128.
//
// R1 change: mask dtype is ambiguous (jnp.bool_ may arrive as 1-byte bool or
// widened int32). Detect on-device: if any of the first 256 dwords of the
// mask buffer is >1, it's byte-packed; else int32. Grid-uniform branch.
// ---------------------------------------------------------------------------

typedef short s16x8 __attribute__((ext_vector_type(8)));   // 8 bf16 bit-patterns
typedef short s16x4 __attribute__((ext_vector_type(4)));
typedef float f32x4 __attribute__((ext_vector_type(4)));

#define BM 128
#define BN 128
#define BK 64
#define LDSS 72   // BK + 8 pad: 144B row stride (16B aligned, 2-way bank max)

static __device__ __forceinline__ short f2bf(float f) {
    __hip_bfloat16 h = __float2bfloat16(f);   // round-to-nearest-even
    return *reinterpret_cast<short*>(&h);
}

// ---------------- dequant: W_q(int32) -> W bf16 bits (short) ----------------
__global__ __launch_bounds__(256)
void dequant_kernel(const int* __restrict__ Wq,
                    const float* __restrict__ scales,
                    const float* __restrict__ zeros,
                    const void* __restrict__ mask_raw,
                    const float* __restrict__ scale2,
                    short* __restrict__ Wb,
                    int O, int I, int G) {
    // --- mask dtype probe (uniform across grid; ~1KB, L2-resident) ---
    __shared__ int lds_flag;
    if (threadIdx.x == 0) lds_flag = 0;
    __syncthreads();
    {
        unsigned v = ((const unsigned*)mask_raw)[threadIdx.x & 255];
        if (v > 1u) lds_flag = 1;          // benign same-value race
    }
    __syncthreads();
    const bool mask_is_byte = (lds_flag != 0);

    long long idx = ((long long)blockIdx.x * 256 + threadIdx.x) * 8;
    if (idx >= (long long)O * I) return;
    int o = (int)(idx / I);
    int i = (int)(idx % I);           // multiple of 8; G=128 -> one group per 8
    int gi = o * (I / G) + i / G;
    float s = scales[gi];
    float z = zeros[gi];

    int4 w0 = *(const int4*)(Wq + idx);
    int4 w1 = *(const int4*)(Wq + idx + 4);
    float4 s2a = *(const float4*)(scale2 + i);
    float4 s2b = *(const float4*)(scale2 + i + 4);

    // gather per-element mask bits under both interpretations
    unsigned m[8];
    if (mask_is_byte) {
        unsigned long long mb = *(const unsigned long long*)((const unsigned char*)mask_raw + idx);
        #pragma unroll
        for (int j = 0; j < 8; ++j) m[j] = (unsigned)((mb >> (8 * j)) & 0xffULL);
    } else {
        int4 ma = *(const int4*)((const int*)mask_raw + idx);
        int4 mbv = *(const int4*)((const int*)mask_raw + idx + 4);
        m[0] = ma.x;  m[1] = ma.y;  m[2] = ma.z;  m[3] = ma.w;
        m[4] = mbv.x; m[5] = mbv.y; m[6] = mbv.z; m[7] = mbv.w;
    }

    float v[8];
    v[0] = ((float)w0.x - z) * s * s2a.x;
    v[1] = ((float)w0.y - z) * s * s2a.y;
    v[2] = ((float)w0.z - z) * s * s2a.z;
    v[3] = ((float)w0.w - z) * s * s2a.w;
    v[4] = ((float)w1.x - z) * s * s2b.x;
    v[5] = ((float)w1.y - z) * s * s2b.y;
    v[6] = ((float)w1.z - z) * s * s2b.z;
    v[7] = ((float)w1.w - z) * s * s2b.w;

    union { s16x8 v; int4 q; } out;
    #pragma unroll
    for (int j = 0; j < 8; ++j) {
        float masked = m[j] ? v[j] : 0.0f;
        out.v[j] = f2bf(masked);
    }
    *(int4*)(Wb + idx) = out.q;
}

// ---------------- bf16 MFMA GEMM:  Out = X(f32) * Wb^T + bias ---------------
__global__ __launch_bounds__(256, 2)
void gemm_kernel(const float* __restrict__ X,
                 const short* __restrict__ Wb,
                 const float* __restrict__ bias,
                 float* __restrict__ Out,
                 int M, int N, int K) {
    __shared__ short As[BM * LDSS];   // 18 KiB
    __shared__ short Bs[BN * LDSS];   // 18 KiB

    const int tid  = threadIdx.x;
    const int m0   = blockIdx.y * BM;
    const int n0   = blockIdx.x * BN;
    const int wave = tid >> 6;
    const int lane = tid & 63;
    const int wm   = (wave >> 1) * 64;   // wave row offset in tile
    const int wn   = (wave & 1) * 64;    // wave col offset in tile
    const int lr   = lane & 15;          // row (A) / col (B) within 16
    const int lq   = lane >> 4;          // quad -> k offset lq*8, C rows lq*4

    f32x4 acc[4][4] = {};

    for (int k0 = 0; k0 < K; k0 += BK) {
        // stage A: 128x64 fp32 -> bf16.  2048 float4 chunks, 8 per thread.
        #pragma unroll
        for (int t = 0; t < 8; ++t) {
            int c   = tid + t * 256;
            int row = c >> 4;            // 16 float4 per 64-wide row
            int col = (c & 15) * 4;
            float4 xv = *(const float4*)(X + (size_t)(m0 + row) * K + k0 + col);
            s16x4 bv;
            bv[0] = f2bf(xv.x); bv[1] = f2bf(xv.y);
            bv[2] = f2bf(xv.z); bv[3] = f2bf(xv.w);
            *(s16x4*)&As[row * LDSS + col] = bv;
        }
        // stage B: 128x64 bf16.  1024 16B chunks, 4 per thread.
        #pragma unroll
        for (int t = 0; t < 4; ++t) {
            int c   = tid + t * 256;
            int row = c >> 3;            // 8 x 16B per 64-wide row
            int col = (c & 7) * 8;
            s16x8 wv = *(const s16x8*)(Wb + (size_t)(n0 + row) * K + k0 + col);
            *(s16x8*)&Bs[row * LDSS + col] = wv;
        }
        __syncthreads();

        #pragma unroll
        for (int kk = 0; kk < BK; kk += 32) {
            s16x8 af[4], bf[4];
            #pragma unroll
            for (int mi = 0; mi < 4; ++mi)
                af[mi] = *(const s16x8*)&As[(wm + mi * 16 + lr) * LDSS + kk + lq * 8];
            #pragma unroll
            for (int ni = 0; ni < 4; ++ni)
                bf[ni] = *(const s16x8*)&Bs[(wn + ni * 16 + lr) * LDSS + kk + lq * 8];
            #pragma unroll
            for (int mi = 0; mi < 4; ++mi)
                #pragma unroll
                for (int ni = 0; ni < 4; ++ni)
                    acc[mi][ni] = __builtin_amdgcn_mfma_f32_16x16x32_bf16(
                        af[mi], bf[ni], acc[mi][ni], 0, 0, 0);
        }
        __syncthreads();
    }

    // epilogue: C/D layout col = lane&15, row = lq*4 + r   (m89/m91 verified)
    #pragma unroll
    for (int ni = 0; ni < 4; ++ni) {
        int nc = n0 + wn + ni * 16 + lr;
        float bv = bias[nc];
        #pragma unroll
        for (int mi = 0; mi < 4; ++mi) {
            int mr = m0 + wm + mi * 16 + lq * 4;
            #pragma unroll
            for (int r = 0; r < 4; ++r)
                Out[(size_t)(mr + r) * N + nc] = acc[mi][ni][r] + bv;
        }
    }
}

// ---------------------------------------------------------------------------
extern "C" void kernel_launch(void* const* d_in, const int* in_sizes, int n_in,
                              void* d_out, int out_size, void* d_ws, size_t ws_size,
                              hipStream_t stream) {
    const float* x      = (const float*)d_in[0];
    const int*   Wq     = (const int*)d_in[1];
    const float* scales = (const float*)d_in[2];
    const float* zeros  = (const float*)d_in[3];
    const void*  mask   = (const void*)d_in[4];   // bool: byte OR int32 (auto-detect)
    const float* scale2 = (const float*)d_in[5];
    const float* bias   = (const float*)d_in[6];
    float*       out    = (float*)d_out;

    const int I = in_sizes[5];                       // 4096
    const int O = in_sizes[6];                       // 4096
    const int M = (int)(in_sizes[0] / I);            // 16384
    const int G = (int)(((long long)O * I) / in_sizes[2]);  // 128

    short* Wb = (short*)d_ws;                        // O*I bf16 = 32 MB

    long long total = (long long)O * I;
    int dq_blocks = (int)((total / 8 + 255) / 256);
    dequant_kernel<<<dq_blocks, 256, 0, stream>>>(Wq, scales, zeros, mask,
                                                  scale2, Wb, O, I, G);

    dim3 grid(O / BN, M / BM);                       // (32, 128)
    gemm_kernel<<<grid, 256, 0, stream>>>(x, Wb, bias, out, M, O, I);
}